// Round 10
// baseline (216.989 us; speedup 1.0000x reference)
//
#include <hip/hip_runtime.h>

// RNN_53214644797476: out = tanh(X @ W^T + hs @ H^T), hs never updated.
// => one GEMM [32768,1024]x[1024,1024]^T + tiny h_term + tanh epilogue.
// Round 10: keep R6's regime (128x128, BK=32, 256 thr, 4 blocks/CU) but
// STOP LDS-staging B: W is 2 MiB = L2-resident (guide Common-mistake #7);
// read B frags straight from global into regs (per-wave, no barrier).
// LDS now A-only, 3 buffers x 8 KB = 24 KB -> 4 blocks/CU PLUS 2-K-step
// A-prefetch (A(kt+2) staged each iter => A(kt+1) has ~1 full K-step in
// flight before its barrier; drain ~free). bg loads issue BEFORE the A
// stage so the compiler's bg-wait is vmcnt(2), never draining fresh A.
// W stored UNSWIZZLED now; X keeps the 4-slot pre-swizzle for ds_read.

typedef __bf16 bf16x8 __attribute__((ext_vector_type(8)));
typedef float f32x4 __attribute__((ext_vector_type(4)));
typedef unsigned short us4 __attribute__((ext_vector_type(4)));

constexpr int M_TOT = 32768;  // SEQ*BATCH
constexpr int K_D = 1024;
constexpr int N_D = 1024;
constexpr int NTK = K_D / 32;  // 32 K-tiles

__device__ __forceinline__ void async16(const void* g, void* l) {
  __builtin_amdgcn_global_load_lds(
      (const __attribute__((address_space(1))) unsigned int*)g,
      (__attribute__((address_space(3))) unsigned int*)l, 16, 0, 0);
}

__device__ __forceinline__ unsigned short f2bf(float f) {
  unsigned int u = __float_as_uint(f);
  u += 0x7FFFu + ((u >> 16) & 1u);  // round-to-nearest-even
  return (unsigned short)(u >> 16);
}

// ---- merged prep ----
// blocks [0, XBLK): X cvt (pre-swizzled); [XBLK,+WBLK): W cvt (PLAIN);
// [XBLK+WBLK,+HBLK): h_term, one block per h.
constexpr int PREP_XBLK = M_TOT * K_D / 4 / 256;  // 32768
constexpr int PREP_WBLK = N_D * K_D / 4 / 256;    // 1024
constexpr int PREP_HBLK = 1024;
constexpr int PREP_GRID = PREP_XBLK + PREP_WBLK + PREP_HBLK;

__global__ __launch_bounds__(256) void prep_kernel(
    const float* __restrict__ X, unsigned short* __restrict__ Xbf,
    const float* __restrict__ W, unsigned short* __restrict__ Wbf,
    const float* __restrict__ hs, const float* __restrict__ Hm,
    float* __restrict__ ht) {
  __shared__ float4 Hrow4[256];
  const int b = blockIdx.x;
  const int tid = threadIdx.x;

  if (b < PREP_XBLK) {
    // X: swizzled store. j indexes half-slots (4 floats each).
    int j = b * 256 + tid;
    int slot = j >> 1, half = j & 1;
    int row = slot >> 7, st = slot & 127;
    int sd = (st & ~3) | ((st & 3) ^ ((row >> 1) & 3));
    float4 a = *reinterpret_cast<const float4*>(X + (size_t)j * 4);
    us4 v;
    v[0] = f2bf(a.x); v[1] = f2bf(a.y); v[2] = f2bf(a.z); v[3] = f2bf(a.w);
    *reinterpret_cast<us4*>(Xbf + (size_t)row * 1024 + sd * 8 + half * 4) = v;
  } else if (b < PREP_XBLK + PREP_WBLK) {
    // W: plain linear store (B no longer goes through LDS).
    int j = (b - PREP_XBLK) * 256 + tid;
    float4 a = *reinterpret_cast<const float4*>(W + (size_t)j * 4);
    us4 v;
    v[0] = f2bf(a.x); v[1] = f2bf(a.y); v[2] = f2bf(a.z); v[3] = f2bf(a.w);
    *reinterpret_cast<us4*>(Wbf + (size_t)j * 4) = v;
  } else {
    // h_term[bb][h] = sum_k hs[bb][k] * Hm[h][k]
    int h = b - (PREP_XBLK + PREP_WBLK);
    Hrow4[tid] = reinterpret_cast<const float4*>(Hm + (size_t)h * 1024)[tid];
    __syncthreads();
    int w = tid >> 6, l = tid & 63;
#pragma unroll 2
    for (int bb = w * 16; bb < w * 16 + 16; ++bb) {
      const float4* hb4 = reinterpret_cast<const float4*>(hs + (size_t)bb * 1024);
      float s = 0.f;
#pragma unroll
      for (int p = 0; p < 4; ++p) {
        float4 x = hb4[l + p * 64];
        float4 y = Hrow4[l + p * 64];
        s += x.x * y.x + x.y * y.y + x.z * y.z + x.w * y.w;
      }
#pragma unroll
      for (int off = 32; off > 0; off >>= 1) s += __shfl_down(s, off, 64);
      if (l == 0) ht[bb * 1024 + h] = s;
    }
  }
}

// ---- main GEMM: C = tanh(A.B^T + ht[m%64][n]) ----
// A: LDS 3-buffer, 2-K-step prefetch, gload_lds, pre-swizzled source.
// B: direct global->reg fragment loads (L2-resident W).
__global__ __launch_bounds__(256, 4) void gemm_tanh(
    const unsigned short* __restrict__ A, const unsigned short* __restrict__ B,
    const float* __restrict__ ht, float* __restrict__ out0,
    float* __restrict__ out1) {
  __shared__ unsigned short As[3][128 * 32];  // 24 KiB total

  // XCD-bijective swizzle (nwg = 2048 % 8 == 0); A-panel sharers co-XCD.
  int bid = blockIdx.x;
  int swz = (bid & 7) * 256 + (bid >> 3);
  int bm = swz >> 3;  // 0..255
  int bn = swz & 7;   // 0..7

  int tid = threadIdx.x;
  int lane = tid & 63, wid = tid >> 6;
  int wr = wid >> 1, wc = wid & 1;
  int fr = lane & 15, kq = lane >> 4;

  // A staging: 512 chunks of 16B; thread t stages chunks t and t+256.
  // chunk c -> row c>>2, stored slot c&3 (source pre-swizzled -> linear).
  int c1 = tid + 256;
  const unsigned short* gA0 =
      A + (size_t)(bm * 128 + (tid >> 2)) * 1024 + (tid & 3) * 8;
  const unsigned short* gA1 =
      A + (size_t)(bm * 128 + (c1 >> 2)) * 1024 + (c1 & 3) * 8;
  // B fragment base: lane reads row (bn*128 + wc*64 + ni*16 + fr), 16B at
  // byte-col (ks + kq*8)*2; plain (unswizzled) layout.
  const unsigned short* gBf =
      B + (size_t)(bn * 128 + wc * 64 + fr) * 1024 + kq * 8;

  f32x4 acc[4][4] = {};

#define STAGE_A(kt, buf)                              \
  {                                                   \
    async16(gA0 + (kt) * 32, &As[buf][tid * 8]);      \
    async16(gA1 + (kt) * 32, &As[buf][c1 * 8]);       \
  }

  // Prologue: stage A(0), A(1); wait A(0) only (counted); barrier.
  STAGE_A(0, 0);
  STAGE_A(1, 1);
  asm volatile("s_waitcnt vmcnt(2)" ::: "memory");
  __builtin_amdgcn_s_barrier();
  asm volatile("" ::: "memory");

  for (int kt = 0; kt < NTK; ++kt) {
    const int cur = kt % 3;
    const int ks = kt * 32;

    // 1. B frags from global (L2). Issued FIRST so they are older than the
    //    A-stage below: compiler's pre-MFMA wait is then vmcnt(2), which
    //    never drains the fresh A(kt+2) loads.
    bf16x8 bg[4];
#pragma unroll
    for (int ni = 0; ni < 4; ++ni)
      bg[ni] = *reinterpret_cast<const bf16x8*>(gBf + (size_t)ni * 16 * 1024 + ks);
    asm volatile("" ::: "memory");  // keep bg issue before A-stage

    // 2. Prefetch A two K-steps ahead.
    if (kt + 2 < NTK) STAGE_A(kt + 2, (kt + 2) % 3);

    // 3. A frags from LDS (swizzled read).
    bf16x8 af[4];
#pragma unroll
    for (int mi = 0; mi < 4; ++mi) {
      int ra = wr * 64 + mi * 16 + fr;
      af[mi] = *reinterpret_cast<const bf16x8*>(
          &As[cur][ra * 32 + (kq ^ ((ra >> 1) & 3)) * 8]);
    }

    // 4. MFMA cluster.
    __builtin_amdgcn_s_setprio(1);
#pragma unroll
    for (int mi = 0; mi < 4; ++mi)
#pragma unroll
      for (int ni = 0; ni < 4; ++ni)
        acc[mi][ni] = __builtin_amdgcn_mfma_f32_16x16x32_bf16(
            af[mi], bg[ni], acc[mi][ni], 0, 0, 0);
    __builtin_amdgcn_s_setprio(0);

    // 5. Ensure A(kt+1) resident (it is oldest; bg-wait already covered it),
    //    keep A(kt+2) in flight; single barrier per K-step.
    if (kt + 1 < NTK) {
      if (kt + 2 < NTK)
        asm volatile("s_waitcnt vmcnt(2)" ::: "memory");
      else
        asm volatile("s_waitcnt vmcnt(0)" ::: "memory");
      __builtin_amdgcn_s_barrier();
      asm volatile("" ::: "memory");
    }
  }

  // Epilogue: y = tanh(acc + ht[m%64][n]); out0 always, out1 for last 64 rows.
  const int nbase = bn * 128 + wc * 64;
#pragma unroll
  for (int mi = 0; mi < 4; ++mi) {
#pragma unroll
    for (int r = 0; r < 4; ++r) {
      int mloc = wr * 64 + mi * 16 + kq * 4 + r;
      size_t m = (size_t)bm * 128 + mloc;
      int b = mloc & 63;
#pragma unroll
      for (int ni = 0; ni < 4; ++ni) {
        int n = nbase + ni * 16 + fr;
        float x = acc[mi][ni][r] + ht[b * 1024 + n];
        float e = __expf(2.0f * x);
        float y = 1.0f - 2.0f / (e + 1.0f);  // tanh(x), safe at +-inf
        out0[m * 1024 + n] = y;
        if (m >= (size_t)(M_TOT - 64))
          out1[(m - (M_TOT - 64)) * 1024 + n] = y;
      }
    }
  }
#undef STAGE_A
}

extern "C" void kernel_launch(void* const* d_in, const int* in_sizes, int n_in,
                              void* d_out, int out_size, void* d_ws,
                              size_t ws_size, hipStream_t stream) {
  (void)in_sizes; (void)n_in; (void)out_size; (void)ws_size;
  const float* X  = (const float*)d_in[0];  // [512,64,1024] = [32768,1024]
  const float* hs = (const float*)d_in[1];  // [64,1024]
  const float* W  = (const float*)d_in[2];  // [1024,1024]
  const float* Hm = (const float*)d_in[3];  // [1024,1024]
  float* out0 = (float*)d_out;               // [32768,1024]
  float* out1 = out0 + (size_t)M_TOT * N_D;  // [64,1024]

  // ws layout: Xbf (64 MiB) | Wbf (2 MiB) | hterm (256 KiB)
  unsigned short* Xbf = (unsigned short*)d_ws;
  unsigned short* Wbf = Xbf + (size_t)M_TOT * K_D;
  float* hterm = (float*)(Wbf + (size_t)N_D * K_D);

  prep_kernel<<<PREP_GRID, 256, 0, stream>>>(X, Xbf, W, Wbf, hs, Hm, hterm);
  gemm_tanh<<<(M_TOT / 128) * (N_D / 128), 256, 0, stream>>>(Xbf, Wbf, hterm,
                                                             out0, out1);
}

// Round 11
// 191.898 us; speedup vs baseline: 1.1308x; 1.1308x over previous
//
#include <hip/hip_runtime.h>

// RNN_53214644797476: out = tanh(X @ W^T + hs @ H^T), hs never updated.
// => one GEMM [32768,1024]x[1024,1024]^T + tiny h_term + tanh epilogue.
// Round 11: eliminate the Xbf round-trip (prep-X was 134MB rd + 67MB wr,
// gemm re-fetched 45MB). GEMM converts X f32->bf16 IN-KERNEL, once per
// element per bn-block, with BN=512 so redundancy is 2x (R3's failure was
// 8x) and the 2nd read is L2/LLC-hit (X < 256MB Infinity Cache; co-XCD
// swizzle pairs the two bn-sharers). B path unchanged from R6/R8's proven
// scheme: pre-swizzled Wbf + gload_lds linear dest + XOR ds_read, 2-barrier
// loop. Block = 512 thr / 8 waves x (64x64), 2 blocks/CU, 16 waves/CU
// (same occupancy regime as R6/R8). LDS 36KB: B[512][32]=32KB + A[64][32]=4KB.

typedef __bf16 bf16x8 __attribute__((ext_vector_type(8)));
typedef float f32x4 __attribute__((ext_vector_type(4)));
typedef unsigned short us4 __attribute__((ext_vector_type(4)));

constexpr int M_TOT = 32768;  // SEQ*BATCH
constexpr int K_D = 1024;
constexpr int N_D = 1024;
constexpr int BM = 64, BN = 512, BKT = 32;

__device__ __forceinline__ void async16(const void* g, void* l) {
  __builtin_amdgcn_global_load_lds(
      (const __attribute__((address_space(1))) unsigned int*)g,
      (__attribute__((address_space(3))) unsigned int*)l, 16, 0, 0);
}

__device__ __forceinline__ unsigned short f2bf(float f) {
  unsigned int u = __float_as_uint(f);
  u += 0x7FFFu + ((u >> 16) & 1u);  // round-to-nearest-even
  return (unsigned short)(u >> 16);
}

// ---- prep: W cvt+swizzle (1024 blocks) | hterm (1024 blocks) ----
// W slot pre-swizzle (matches gemm read XOR): 16B slot st of row stored at
// sd = (st&~3) | ((st&3) ^ ((row>>1)&3)).
constexpr int PREP_WBLK = N_D * K_D / 4 / 256;  // 1024
constexpr int PREP_HBLK = 1024;
constexpr int PREP_GRID = PREP_WBLK + PREP_HBLK;

__global__ __launch_bounds__(256) void prep_kernel(
    const float* __restrict__ W, unsigned short* __restrict__ Wbf,
    const float* __restrict__ hs, const float* __restrict__ Hm,
    float* __restrict__ ht) {
  __shared__ float4 Hrow4[256];
  const int b = blockIdx.x;
  const int tid = threadIdx.x;

  if (b < PREP_WBLK) {
    // j indexes half-slots (4 floats each).
    int j = b * 256 + tid;
    int slot = j >> 1, half = j & 1;
    int row = slot >> 7, st = slot & 127;
    int sd = (st & ~3) | ((st & 3) ^ ((row >> 1) & 3));
    float4 a = *reinterpret_cast<const float4*>(W + (size_t)j * 4);
    us4 v;
    v[0] = f2bf(a.x); v[1] = f2bf(a.y); v[2] = f2bf(a.z); v[3] = f2bf(a.w);
    *reinterpret_cast<us4*>(Wbf + (size_t)row * 1024 + sd * 8 + half * 4) = v;
  } else {
    // h_term[bb][h] = sum_k hs[bb][k] * Hm[h][k]
    int h = b - PREP_WBLK;
    Hrow4[tid] = reinterpret_cast<const float4*>(Hm + (size_t)h * 1024)[tid];
    __syncthreads();
    int w = tid >> 6, l = tid & 63;
#pragma unroll 2
    for (int bb = w * 16; bb < w * 16 + 16; ++bb) {
      const float4* hb4 = reinterpret_cast<const float4*>(hs + (size_t)bb * 1024);
      float s = 0.f;
#pragma unroll
      for (int p = 0; p < 4; ++p) {
        float4 x = hb4[l + p * 64];
        float4 y = Hrow4[l + p * 64];
        s += x.x * y.x + x.y * y.y + x.z * y.z + x.w * y.w;
      }
#pragma unroll
      for (int off = 32; off > 0; off >>= 1) s += __shfl_down(s, off, 64);
      if (l == 0) ht[bb * 1024 + h] = s;
    }
  }
}

// ---- fused GEMM: C = tanh(X_f32[M,K].Wbf[N,K]^T + ht[m%64][n]) ----
// 64x512 tile, 8 waves of 64x64, BK=32, 2-barrier loop.
__global__ __launch_bounds__(512, 4) void gemm_fused(
    const float* __restrict__ X, const unsigned short* __restrict__ B,
    const float* __restrict__ ht, float* __restrict__ out0,
    float* __restrict__ out1) {
  __shared__ unsigned short Bs[BN * BKT];  // 32 KiB
  __shared__ unsigned short As[BM * BKT];  // 4 KiB

  // XCD swizzle: xcd = bid&7 gets contiguous 64 bm x both bn (bijective,
  // nwg = 1024). The 2 bn-sharers of an A-panel are adjacent -> co-XCD.
  int bid = blockIdx.x;
  int idx = bid >> 3;
  int bm = (bid & 7) * 64 + (idx >> 1);  // 0..511
  int bn = idx & 1;                      // 0..1

  int tid = threadIdx.x;
  int lane = tid & 63, wid = tid >> 6;  // 8 waves, each 64x64 output
  int fr = lane & 15, kq = lane >> 4;

  // B staging: 2048 chunks of 16B; thread stages 4 (c = tid + i*512).
  // chunk c -> row c>>2, stored slot c&3; source pre-swizzled -> linear.
  const unsigned short* gB[4];
#pragma unroll
  for (int i = 0; i < 4; ++i) {
    int c = tid + i * 512;
    gB[i] = B + (size_t)(bn * BN + (c >> 2)) * 1024 + (c & 3) * 8;
  }
  // A (X f32): thread t loads float4 at row t>>3, k-col (t&7)*4.
  const float* gX = X + (size_t)(bm * BM + (tid >> 3)) * 1024 + (tid & 7) * 4;
  // A LDS write position (swizzled): row r, slot s=(t&7)>>1, half=t&1.
  const int awr = tid >> 3;
  const int aws = ((tid & 7) >> 1) ^ ((awr >> 1) & 3);
  unsigned short* aw = &As[awr * 32 + aws * 8 + (tid & 1) * 4];

  f32x4 acc[4][4] = {};

  for (int ks = 0; ks < K_D; ks += BKT) {
    // A f32 load first (oldest), then B gload_lds; the ds_write's wait
    // can then leave B in flight (barrier drains all anyway).
    float4 a4 = *reinterpret_cast<const float4*>(gX + ks);
#pragma unroll
    for (int i = 0; i < 4; ++i)
      async16(gB[i] + ks, &Bs[(tid + i * 512) * 8]);
    us4 v;
    v[0] = f2bf(a4.x); v[1] = f2bf(a4.y); v[2] = f2bf(a4.z); v[3] = f2bf(a4.w);
    *reinterpret_cast<us4*>(aw) = v;
    __syncthreads();  // drains vmcnt+lgkmcnt: B staged, A written

    bf16x8 af[4], bg[4];
#pragma unroll
    for (int mi = 0; mi < 4; ++mi) {
      int ra = mi * 16 + fr;  // all waves share A rows (LDS broadcast)
      af[mi] = *reinterpret_cast<const bf16x8*>(
          &As[ra * 32 + (kq ^ ((ra >> 1) & 3)) * 8]);
    }
#pragma unroll
    for (int ni = 0; ni < 4; ++ni) {
      int rb = wid * 64 + ni * 16 + fr;
      bg[ni] = *reinterpret_cast<const bf16x8*>(
          &Bs[rb * 32 + (kq ^ ((rb >> 1) & 3)) * 8]);
    }
#pragma unroll
    for (int mi = 0; mi < 4; ++mi)
#pragma unroll
      for (int ni = 0; ni < 4; ++ni)
        acc[mi][ni] = __builtin_amdgcn_mfma_f32_16x16x32_bf16(
            af[mi], bg[ni], acc[mi][ni], 0, 0, 0);
    __syncthreads();  // before next stage overwrites LDS
  }

  // Epilogue: y = tanh(acc + ht[m%64][n]); out0 always, out1 for last 64 rows.
  const int nbase = bn * BN + wid * 64;
#pragma unroll
  for (int mi = 0; mi < 4; ++mi) {
#pragma unroll
    for (int r = 0; r < 4; ++r) {
      int mloc = mi * 16 + kq * 4 + r;  // 0..63
      size_t m = (size_t)bm * BM + mloc;
      int b = mloc;  // m % 64 (BM = 64)
#pragma unroll
      for (int ni = 0; ni < 4; ++ni) {
        int n = nbase + ni * 16 + fr;
        float x = acc[mi][ni][r] + ht[b * 1024 + n];
        float e = __expf(2.0f * x);
        float y = 1.0f - 2.0f / (e + 1.0f);  // tanh(x), safe at +-inf
        out0[m * 1024 + n] = y;
        if (m >= (size_t)(M_TOT - 64))
          out1[(m - (M_TOT - 64)) * 1024 + n] = y;
      }
    }
  }
}

extern "C" void kernel_launch(void* const* d_in, const int* in_sizes, int n_in,
                              void* d_out, int out_size, void* d_ws,
                              size_t ws_size, hipStream_t stream) {
  (void)in_sizes; (void)n_in; (void)out_size; (void)ws_size;
  const float* X  = (const float*)d_in[0];  // [512,64,1024] = [32768,1024]
  const float* hs = (const float*)d_in[1];  // [64,1024]
  const float* W  = (const float*)d_in[2];  // [1024,1024]
  const float* Hm = (const float*)d_in[3];  // [1024,1024]
  float* out0 = (float*)d_out;               // [32768,1024]
  float* out1 = out0 + (size_t)M_TOT * N_D;  // [64,1024]

  // ws layout: Wbf (2 MiB) | hterm (256 KiB)
  unsigned short* Wbf = (unsigned short*)d_ws;
  float* hterm = (float*)(Wbf + (size_t)N_D * K_D);

  prep_kernel<<<PREP_GRID, 256, 0, stream>>>(W, Wbf, hs, Hm, hterm);
  gemm_fused<<<(M_TOT / BM) * (N_D / BN), 512, 0, stream>>>(X, Wbf, hterm,
                                                            out0, out1);
}

// Round 12
// 155.735 us; speedup vs baseline: 1.3933x; 1.2322x over previous
//
#include <hip/hip_runtime.h>

// RNN_53214644797476: out = tanh(X @ W^T + hs @ H^T), hs never updated.
// => one GEMM [32768,1024]x[1024,1024]^T + tiny h_term + tanh epilogue.
// Round 12: R8's tile (256x128, 512 thr, 8 waves 64x64, BK=32) + R4's
// 2-deep 3-buffer counted-vmcnt pipeline, now WITHOUT the occupancy
// penalty: 3 x 24 KB = 72 KB LDS -> 2 blocks/CU x 8 waves = 16 waves/CU
// (same as R6/R8). Stage kt+2 each iter; vmcnt(3) waits only kt+1's
// loads (kt+2's stay in flight across the barrier; never drains to 0
// in-loop). Tests the last untested cell: 2-K-step latency cover at
// full 16-wave occupancy. Prep identical to R8 (4-slot pre-swizzle).

typedef __bf16 bf16x8 __attribute__((ext_vector_type(8)));
typedef float f32x4 __attribute__((ext_vector_type(4)));
typedef unsigned short us4 __attribute__((ext_vector_type(4)));

constexpr int M_TOT = 32768;  // SEQ*BATCH
constexpr int K_D = 1024;
constexpr int N_D = 1024;
constexpr int BM = 256, BN = 128, BKT = 32;
constexpr int NTK = K_D / BKT;  // 32 K-tiles
constexpr int ATILE = BM * BKT; // 8192 ushorts = 16 KiB
constexpr int BTILE = BN * BKT; // 4096 ushorts = 8 KiB

__device__ __forceinline__ void async16(const void* g, void* l) {
  __builtin_amdgcn_global_load_lds(
      (const __attribute__((address_space(1))) unsigned int*)g,
      (__attribute__((address_space(3))) unsigned int*)l, 16, 0, 0);
}

__device__ __forceinline__ unsigned short f2bf(float f) {
  unsigned int u = __float_as_uint(f);
  u += 0x7FFFu + ((u >> 16) & 1u);  // round-to-nearest-even
  return (unsigned short)(u >> 16);
}

// ---- merged prep (identical to round 6/8) ----
// blocks [0, XBLK): X cvt, one float4 per thread; [XBLK,+WBLK): W cvt;
// [XBLK+WBLK,+HBLK): h_term, one block per h.
// Slot pre-swizzle (matches gemm read XOR): 16B slot st of row stored at
// sd = (st&~3) | ((st&3) ^ ((row>>1)&3)).
constexpr int PREP_XBLK = M_TOT * K_D / 4 / 256;  // 32768
constexpr int PREP_WBLK = N_D * K_D / 4 / 256;    // 1024
constexpr int PREP_HBLK = 1024;
constexpr int PREP_GRID = PREP_XBLK + PREP_WBLK + PREP_HBLK;

__global__ __launch_bounds__(256) void prep_kernel(
    const float* __restrict__ X, unsigned short* __restrict__ Xbf,
    const float* __restrict__ W, unsigned short* __restrict__ Wbf,
    const float* __restrict__ hs, const float* __restrict__ Hm,
    float* __restrict__ ht) {
  __shared__ float4 Hrow4[256];
  const int b = blockIdx.x;
  const int tid = threadIdx.x;

  if (b < PREP_XBLK + PREP_WBLK) {
    const float* in = (b < PREP_XBLK) ? X : W;
    unsigned short* out = (b < PREP_XBLK) ? Xbf : Wbf;
    int j = (b < PREP_XBLK) ? (b * 256 + tid) : ((b - PREP_XBLK) * 256 + tid);
    // j indexes half-slots (4 floats each).
    int slot = j >> 1, half = j & 1;
    int row = slot >> 7, st = slot & 127;
    int sd = (st & ~3) | ((st & 3) ^ ((row >> 1) & 3));
    float4 a = *reinterpret_cast<const float4*>(in + (size_t)j * 4);
    us4 v;
    v[0] = f2bf(a.x); v[1] = f2bf(a.y); v[2] = f2bf(a.z); v[3] = f2bf(a.w);
    *reinterpret_cast<us4*>(out + (size_t)row * 1024 + sd * 8 + half * 4) = v;
  } else {
    // h_term[bb][h] = sum_k hs[bb][k] * Hm[h][k]
    int h = b - (PREP_XBLK + PREP_WBLK);
    Hrow4[tid] = reinterpret_cast<const float4*>(Hm + (size_t)h * 1024)[tid];
    __syncthreads();
    int w = tid >> 6, l = tid & 63;
#pragma unroll 2
    for (int bb = w * 16; bb < w * 16 + 16; ++bb) {
      const float4* hb4 = reinterpret_cast<const float4*>(hs + (size_t)bb * 1024);
      float s = 0.f;
#pragma unroll
      for (int p = 0; p < 4; ++p) {
        float4 x = hb4[l + p * 64];
        float4 y = Hrow4[l + p * 64];
        s += x.x * y.x + x.y * y.y + x.z * y.z + x.w * y.w;
      }
#pragma unroll
      for (int off = 32; off > 0; off >>= 1) s += __shfl_down(s, off, 64);
      if (l == 0) ht[bb * 1024 + h] = s;
    }
  }
}

// ---- main GEMM: C = tanh(A.B^T + ht[m%64][n]) ----
// 256x128 tile, 8 waves (4x2) of 64x64, 3-buffer 2-deep counted-vmcnt.
__global__ __launch_bounds__(512, 4) void gemm_tanh(
    const unsigned short* __restrict__ A, const unsigned short* __restrict__ B,
    const float* __restrict__ ht, float* __restrict__ out0,
    float* __restrict__ out1) {
  __shared__ unsigned short As[3][ATILE];  // 48 KiB
  __shared__ unsigned short Bs[3][BTILE];  // 24 KiB

  // XCD-bijective swizzle (nwg = 1024 % 8 == 0); A-panel sharers co-XCD.
  int bid = blockIdx.x;
  int swz = (bid & 7) * 128 + (bid >> 3);
  int bm = swz >> 3;  // 0..127
  int bn = swz & 7;   // 0..7

  int tid = threadIdx.x;
  int lane = tid & 63, wid = tid >> 6;
  int wr = wid >> 1, wc = wid & 1;  // 4 x 2 waves, each 64x64 output
  int fr = lane & 15, kq = lane >> 4;

  // Staging: A = 1024 chunks (256 rows x 4 slots), B = 512 chunks.
  // Thread t stages A chunks t, t+512 and B chunk t. LDS dest linear;
  // global source pre-swizzled, so source addrs are linear too.
  int c1 = tid + 512;
  const unsigned short* gA0 =
      A + (size_t)(bm * BM + (tid >> 2)) * 1024 + (tid & 3) * 8;
  const unsigned short* gA1 =
      A + (size_t)(bm * BM + (c1 >> 2)) * 1024 + (tid & 3) * 8;
  const unsigned short* gB0 =
      B + (size_t)(bn * BN + (tid >> 2)) * 1024 + (tid & 3) * 8;

  f32x4 acc[4][4] = {};

#define STAGE(kt, buf)                                  \
  {                                                     \
    async16(gA0 + (kt) * BKT, &As[buf][tid * 8]);       \
    async16(gA1 + (kt) * BKT, &As[buf][c1 * 8]);        \
    async16(gB0 + (kt) * BKT, &Bs[buf][tid * 8]);       \
  }

  // Prologue: stage tiles 0 and 1; wait tile 0 only (counted); barrier.
  STAGE(0, 0);
  STAGE(1, 1);
  asm volatile("s_waitcnt vmcnt(3)" ::: "memory");
  __builtin_amdgcn_s_barrier();
  asm volatile("" ::: "memory");

  for (int kt = 0; kt < NTK; ++kt) {
    const int cur = kt % 3;
    // Stage 2 K-steps ahead; these loads fly across this iter's barrier.
    if (kt + 2 < NTK) STAGE(kt + 2, (kt + 2) % 3);

    bf16x8 af[4], bg[4];
#pragma unroll
    for (int mi = 0; mi < 4; ++mi) {
      int ra = wr * 64 + mi * 16 + fr;
      af[mi] = *reinterpret_cast<const bf16x8*>(
          &As[cur][ra * BKT + (kq ^ ((ra >> 1) & 3)) * 8]);
    }
#pragma unroll
    for (int ni = 0; ni < 4; ++ni) {
      int rb = wc * 64 + ni * 16 + fr;
      bg[ni] = *reinterpret_cast<const bf16x8*>(
          &Bs[cur][rb * BKT + (kq ^ ((rb >> 1) & 3)) * 8]);
    }
    __builtin_amdgcn_s_setprio(1);
#pragma unroll
    for (int mi = 0; mi < 4; ++mi)
#pragma unroll
      for (int ni = 0; ni < 4; ++ni)
        acc[mi][ni] = __builtin_amdgcn_mfma_f32_16x16x32_bf16(
            af[mi], bg[ni], acc[mi][ni], 0, 0, 0);
    __builtin_amdgcn_s_setprio(0);

    if (kt + 1 < NTK) {
      // Counted drain: ensure kt+1 resident (its 3 loads are the oldest),
      // keep kt+2's 3 loads in flight across the barrier.
      if (kt + 2 < NTK)
        asm volatile("s_waitcnt vmcnt(3)" ::: "memory");
      else
        asm volatile("s_waitcnt vmcnt(0)" ::: "memory");
      __builtin_amdgcn_s_barrier();
      asm volatile("" ::: "memory");
    }
  }

  // Epilogue: y = tanh(acc + ht[m%64][n]); out0 always, out1 for last 64 rows.
  const int nbase = bn * BN + wc * 64;
#pragma unroll
  for (int mi = 0; mi < 4; ++mi) {
#pragma unroll
    for (int r = 0; r < 4; ++r) {
      int mloc = wr * 64 + mi * 16 + kq * 4 + r;  // 0..255
      size_t m = (size_t)bm * BM + mloc;
      int b = mloc & 63;  // m % 64 (BM multiple of 64)
#pragma unroll
      for (int ni = 0; ni < 4; ++ni) {
        int n = nbase + ni * 16 + fr;
        float x = acc[mi][ni][r] + ht[b * 1024 + n];
        float e = __expf(2.0f * x);
        float y = 1.0f - 2.0f / (e + 1.0f);  // tanh(x), safe at +-inf
        out0[m * 1024 + n] = y;
        if (m >= (size_t)(M_TOT - 64))
          out1[(m - (M_TOT - 64)) * 1024 + n] = y;
      }
    }
  }
#undef STAGE
}

extern "C" void kernel_launch(void* const* d_in, const int* in_sizes, int n_in,
                              void* d_out, int out_size, void* d_ws,
                              size_t ws_size, hipStream_t stream) {
  (void)in_sizes; (void)n_in; (void)out_size; (void)ws_size;
  const float* X  = (const float*)d_in[0];  // [512,64,1024] = [32768,1024]
  const float* hs = (const float*)d_in[1];  // [64,1024]
  const float* W  = (const float*)d_in[2];  // [1024,1024]
  const float* Hm = (const float*)d_in[3];  // [1024,1024]
  float* out0 = (float*)d_out;               // [32768,1024]
  float* out1 = out0 + (size_t)M_TOT * N_D;  // [64,1024]

  // ws layout: Xbf (64 MiB) | Wbf (2 MiB) | hterm (256 KiB)
  unsigned short* Xbf = (unsigned short*)d_ws;
  unsigned short* Wbf = Xbf + (size_t)M_TOT * K_D;
  float* hterm = (float*)(Wbf + (size_t)N_D * K_D);

  prep_kernel<<<PREP_GRID, 256, 0, stream>>>(X, Xbf, W, Wbf, hs, Hm, hterm);
  gemm_tanh<<<(M_TOT / BM) * (N_D / BN), 512, 0, stream>>>(Xbf, Wbf, hterm,
                                                           out0, out1);
}